// Round 10
// baseline (125.335 us; speedup 1.0000x reference)
//
#include <hip/hip_runtime.h>
#include <hip/hip_bf16.h>

#define ROWS_TOTAL 8192   // 4 * 2048
#define EMB 1024
#define HEAD 64
#define SEQ 2048
#define KSPLIT 8                // attn k-chunks (blockIdx.y)
#define KC (SEQ / KSPLIT)       // 256 keys per attn block

typedef __attribute__((ext_vector_type(8))) short short8;   // 8 bf16 = 4 VGPRs
typedef __attribute__((ext_vector_type(4))) float f32x4;

#define MFMA16(a, b, c) __builtin_amdgcn_mfma_f32_16x16x32_bf16((a), (b), (c), 0, 0, 0)

static __device__ __forceinline__ unsigned short f2bf(float f) {
    union { float f; unsigned u; } v; v.f = f;
    unsigned r = v.u + 0x7fff + ((v.u >> 16) & 1);   // RNE
    return (unsigned short)(r >> 16);
}

// packed f32x2 -> bf16x2 (v_cvt_pk_bf16_f32 on gfx950): low16 = a, high16 = b
static __device__ __forceinline__ unsigned pk2(float a, float b) {
    __hip_bfloat162 h = __float22bfloat162_rn(float2{a, b});
    union { __hip_bfloat162 h; unsigned u; } v; v.h = h;
    return v.u;
}

// ---------------------------------------------------------------------------
// Fragment-order layouts (the R8-proven Wf trick, extended to K and V):
//  Wf[kc32][tile][ln][quad][8]                      (weights, B-frag for QKV)
//  Kf[b][keytile(128)][dchunk(2)][ln(16)][quad(4)][8]   (B-frag for QK^T)
//      element (key,d) -> [b][key>>4][d>>5][key&15][(d>>3)&3][d&7]
//  Vf[b][kchunk(64)][dtile(4)][ln(16)][quad(4)][8]      (B-frag for PV)
//      element (key,d) -> [b][key>>5][d>>4][d&15][(key>>3)&3][key&7]
// A wave's fragment load = dense 1 KB (64 lanes x 16B, disjoint) from L2.
// ---------------------------------------------------------------------------

// ---------------------------------------------------------------------------
// Kernel 0: W -> Wf (R8-verified, unchanged). grid = (16, 3) x 256.
// ---------------------------------------------------------------------------
__global__ __launch_bounds__(256) void wprep_kernel(
    const float* __restrict__ Wq, const float* __restrict__ Wk,
    const float* __restrict__ Wv, unsigned short* __restrict__ Wf)
{
    __shared__ float Tr[64][65];
    const int m  = blockIdx.y;
    const int k0 = blockIdx.x * 64;
    const float* __restrict__ W = (m == 0) ? Wq : (m == 1) ? Wk : Wv;
    const int t = threadIdx.x;

    #pragma unroll
    for (int j = 0; j < 4; ++j) {
        int flat = j * 1024 + t * 4;          // 0..4095
        int k = flat >> 6, n = flat & 63;
        float4 w4 = *(const float4*)&W[(size_t)(k0 + k) * 64 + n];
        Tr[n + 0][k] = w4.x; Tr[n + 1][k] = w4.y;
        Tr[n + 2][k] = w4.z; Tr[n + 3][k] = w4.w;
    }
    __syncthreads();

    const int n   = t >> 2;                   // col 0..63
    const int k16 = t & 3;                    // 16-k chunk within slab
    union { short8 s; unsigned u[4]; } o0, o1;
    #pragma unroll
    for (int i = 0; i < 4; ++i) {
        o0.u[i] = pk2(Tr[n][k16 * 16 + 2 * i],     Tr[n][k16 * 16 + 2 * i + 1]);
        o1.u[i] = pk2(Tr[n][k16 * 16 + 8 + 2 * i], Tr[n][k16 * 16 + 9 + 2 * i]);
    }
    const int tile = m * 4 + (n >> 4);
    const int ln   = n & 15;
    const int kc32 = (k0 >> 5) + (k16 >> 1);
    const int half = k16 & 1;
    size_t off = ((size_t)(kc32 * 12 + tile) * 16 + ln) * 32 + half * 16;
    *(short8*)&Wf[off]     = o0.s;
    *(short8*)&Wf[off + 8] = o1.s;
}

// ---------------------------------------------------------------------------
// Kernel 1: QKV projection — R8-verified core (16 rows/block, grid 512,
// block 512, cooperative X staging, dense Wf B-frags, kh pair-reduce).
// Epilogue now writes Q row-major (pre-scaled), K into Kf frag order,
// V into Vf frag order (via vlds transpose).
// ---------------------------------------------------------------------------
__global__ __launch_bounds__(512) void qkv_mfma(
    const float* __restrict__ x, const unsigned short* __restrict__ Wf,
    const float* __restrict__ bq, const float* __restrict__ bk,
    const float* __restrict__ bv,
    unsigned short* __restrict__ Qb, unsigned short* __restrict__ Kf,
    unsigned short* __restrict__ Vf)
{
    __shared__ unsigned short Xl[16][136];     // 4.25 KB staged X (272B rows)
    __shared__ f32x4 pr[4][3][64];             // 12 KB kh=1 partials
    __shared__ unsigned short vlds[64][20];

    const int t    = threadIdx.x;
    const int w    = t >> 6;
    const int lane = t & 63;
    const int ln   = lane & 15;
    const int quad = lane >> 4;
    const int m0   = blockIdx.x * 16;
    const int cg   = w >> 1;                   // col group 0..3
    const int kh   = w & 1;                    // k sub-half

    const f32x4 zero = (f32x4){0.f, 0.f, 0.f, 0.f};
    f32x4 acc[3];
    #pragma unroll
    for (int j = 0; j < 3; ++j) acc[j] = zero;

    // staging map: thread -> (row, 4 floats), coalesced within rows
    const int srow = t >> 5;                   // 0..15
    const int scol = (t & 31) * 4;             // 0..124
    const float* __restrict__ xsrc = x + (size_t)(m0 + srow) * EMB + scol;

    for (int kt = 0; kt < EMB; kt += 128) {
        float4 xv = *(const float4*)(xsrc + kt);
        uint2 pk; pk.x = pk2(xv.x, xv.y); pk.y = pk2(xv.z, xv.w);
        *(uint2*)&Xl[srow][scol] = pk;
        __syncthreads();

        #pragma unroll
        for (int cc = 0; cc < 2; ++cc) {
            short8 af = *(const short8*)&Xl[ln][kh * 64 + cc * 32 + quad * 8];
            const int kc32 = (kt >> 5) + kh * 2 + cc;
            #pragma unroll
            for (int j = 0; j < 3; ++j) {
                const int tile = cg * 3 + j;
                short8 bf = *(const short8*)
                    (Wf + ((size_t)(kc32 * 12 + tile) * 16 + ln) * 32 + quad * 8);
                acc[j] = MFMA16(af, bf, acc[j]);
            }
        }
        __syncthreads();
    }

    if (kh == 1) {
        #pragma unroll
        for (int j = 0; j < 3; ++j) pr[cg][j][lane] = acc[j];
    }
    __syncthreads();

    const int b2 = m0 >> 11;                   // batch
    const int s0 = m0 & 2047;                  // seq offset within batch

    if (kh == 0) {
        const float qs = 0.125f * 1.44269504f;   // softmax scale * log2(e)
        const int st = s0 >> 4;                  // key-tile
        #pragma unroll
        for (int j = 0; j < 3; ++j) {
            acc[j] += pr[cg][j][lane];
            const int tile = cg * 3 + j;
            const int mat  = tile >> 2;
            const int d    = (tile & 3) * 16 + ln;
            const float* bp = (mat == 0) ? bq : (mat == 1) ? bk : bv;
            const float bias = bp[d];
            #pragma unroll
            for (int r = 0; r < 4; ++r) {
                float vfull = acc[j][r] + bias;
                int row = m0 + quad * 4 + r;
                if (mat == 0) {
                    Qb[(size_t)row * 64 + d] = f2bf(vfull * qs);
                } else if (mat == 1) {
                    // Kf[b2][st][d>>5][key&15][(d>>3)&3][d&7]
                    size_t off = ((((size_t)(b2 * 128 + st) * 2 + (d >> 5)) * 16
                                   + (quad * 4 + r)) * 4 + ((d >> 3) & 3)) * 8 + (d & 7);
                    Kf[off] = f2bf(vfull);
                } else {
                    vlds[d][quad * 4 + r] = f2bf(vfull);
                }
            }
        }
    }
    __syncthreads();

    if (t < 256) {   // Vf[b2][s0>>5][d>>4][d&15][(key>>3)&3][key&7], 8B/thread
        const int d  = t >> 2;
        const int kq = (t & 3) * 4;            // key offset within 16-row block
        const int key = s0 + kq;               // first of 4 consecutive keys
        ushort4 pk = {vlds[d][kq + 0], vlds[d][kq + 1],
                      vlds[d][kq + 2], vlds[d][kq + 3]};
        size_t off = ((((size_t)(b2 * 64 + (key >> 5)) * 4 + (d >> 4)) * 16
                       + (d & 15)) * 4 + ((key >> 3) & 3)) * 8 + (key & 7);
        *(ushort4*)&Vf[off] = pk;
    }
}

// ---------------------------------------------------------------------------
// Kernel 2: MFMA flash attention, BARRIER-FREE k-loop. grid = (64, 8),
// block = 512 (8 waves). Wave w owns q-rows [bx*128+w*16, +16); all K/V
// fragments are dense 1 KB wave-loads from frag-ordered Kf/Vf (L2-resident).
// LDS only for the per-wave P C->A round-trip (no __syncthreads in loop).
// ---------------------------------------------------------------------------
__global__ __launch_bounds__(512) void attn_mfma(
    const unsigned short* __restrict__ Qb, const unsigned short* __restrict__ Kf,
    const unsigned short* __restrict__ Vf,
    float* __restrict__ Opart, float* __restrict__ lpart)
{
    __shared__ unsigned short Plds[8][16][40];   // 10.2 KB: per-wave 16q x 32k

    const int t    = threadIdx.x;
    const int w    = t >> 6;
    const int lane = t & 63;
    const int ln   = lane & 15;
    const int quad = lane >> 4;

    const int c  = blockIdx.y;                   // k-chunk
    const int q0 = blockIdx.x * 128 + w * 16;    // this wave's q-rows
    const int b  = blockIdx.x >> 4;              // batch (128 rows/block)

    const unsigned short* qbase = Qb + (size_t)(q0 + ln) * 64 + quad * 8;
    short8 qa0 = *(const short8*)(qbase);        // pre-scaled in qkv
    short8 qa1 = *(const short8*)(qbase + 32);

    const f32x4 zero = (f32x4){0.f, 0.f, 0.f, 0.f};
    f32x4 O[4];
    #pragma unroll
    for (int j = 0; j < 4; ++j) O[j] = zero;
    float lacc[4] = {0.f, 0.f, 0.f, 0.f};

    const int lnq = (ln * 4 + quad) * 8;         // lane offset within fragment
    const unsigned short* Kfb = Kf + (size_t)b * 128 * 1024;  // keytile stride 1024
    const unsigned short* Vfb = Vf + (size_t)b * 64 * 2048;   // kchunk stride 2048
    unsigned short* P = &Plds[w][0][0];

    for (int kt = 0; kt < KC; kt += 32) {
        const int gk    = c * KC + kt;
        const int ktile = gk >> 4;
        const int kch   = gk >> 5;

        // ---- QK^T: 2 key-subtiles x 2 emb-chunks, dense frag loads
        short8 k00 = *(const short8*)(Kfb + (size_t)ktile * 1024 + lnq);
        short8 k01 = *(const short8*)(Kfb + (size_t)ktile * 1024 + 512 + lnq);
        short8 k10 = *(const short8*)(Kfb + (size_t)(ktile + 1) * 1024 + lnq);
        short8 k11 = *(const short8*)(Kfb + (size_t)(ktile + 1) * 1024 + 512 + lnq);

        f32x4 sA = MFMA16(qa0, k00, zero); sA = MFMA16(qa1, k01, sA);
        f32x4 sB = MFMA16(qa0, k10, zero); sB = MFMA16(qa1, k11, sB);

        // ---- p = exp2(s); denominator; stage P (C-layout -> A-layout)
        #pragma unroll
        for (int r = 0; r < 4; ++r) {
            float pA = __builtin_amdgcn_exp2f(sA[r]);
            float pB = __builtin_amdgcn_exp2f(sB[r]);
            lacc[r] += pA + pB;
            unsigned u = pk2(pA, pB);
            unsigned short* prow = P + (quad * 4 + r) * 40;
            prow[ln]      = (unsigned short)u;
            prow[16 + ln] = (unsigned short)(u >> 16);
        }
        short8 pa = *(const short8*)&Plds[w][ln][quad * 8];

        // ---- PV: 4 d-tiles, dense frag loads from Vf
        #pragma unroll
        for (int j = 0; j < 4; ++j) {
            short8 vb = *(const short8*)
                (Vfb + (size_t)(kch * 4 + j) * 512 + lnq);
            O[j] = MFMA16(pa, vb, O[j]);
        }
    }

    // denominator: reduce across the 16 key-columns of the C tile
    #pragma unroll
    for (int m = 1; m < 16; m <<= 1) {
        #pragma unroll
        for (int r = 0; r < 4; ++r) lacc[r] += __shfl_xor(lacc[r], m);
    }

    float* __restrict__ ob = Opart + ((size_t)c * ROWS_TOTAL + q0) * 64;
    #pragma unroll
    for (int j = 0; j < 4; ++j)
        #pragma unroll
        for (int r = 0; r < 4; ++r)
            ob[(size_t)(quad * 4 + r) * 64 + j * 16 + ln] = O[j][r];

    if (ln == 0) {
        #pragma unroll
        for (int r = 0; r < 4; ++r)
            lpart[(size_t)c * ROWS_TOTAL + q0 + quad * 4 + r] = lacc[r];
    }
}

// ---------------------------------------------------------------------------
// Kernel 3: combine k-split partials:  out = sum_c O_c / sum_c l_c
// ---------------------------------------------------------------------------
__global__ __launch_bounds__(256) void reduce_kernel(
    const float* __restrict__ Opart, const float* __restrict__ lpart,
    float* __restrict__ out)
{
    const int idx = blockIdx.x * 256 + threadIdx.x;   // [0, 8192*64)
    const int r   = idx >> 6;
    float osum = 0.f, lsum = 0.f;
    #pragma unroll
    for (int c = 0; c < KSPLIT; ++c) {
        osum += Opart[(size_t)c * ROWS_TOTAL * HEAD + idx];
        lsum += lpart[(size_t)c * ROWS_TOTAL + r];
    }
    out[idx] = osum / lsum;
}

// ---------------------------------------------------------------------------
extern "C" void kernel_launch(void* const* d_in, const int* in_sizes, int n_in,
                              void* d_out, int out_size, void* d_ws, size_t ws_size,
                              hipStream_t stream)
{
    const float* x  = (const float*)d_in[0];
    const float* Wq = (const float*)d_in[1];
    const float* bq = (const float*)d_in[2];
    const float* Wk = (const float*)d_in[3];
    const float* bk = (const float*)d_in[4];
    const float* Wv = (const float*)d_in[5];
    const float* bv = (const float*)d_in[6];
    float* out = (float*)d_out;

    char* ws = (char*)d_ws;
    unsigned short* Qb = (unsigned short*)ws;                       // 1 MB
    unsigned short* Kf = Qb + (size_t)ROWS_TOTAL * HEAD;            // 1 MB
    unsigned short* Vf = Kf + (size_t)ROWS_TOTAL * HEAD;            // 1 MB
    unsigned short* Wf = Vf + (size_t)ROWS_TOTAL * HEAD;            // 384 KB
    float* lpart = (float*)(Wf + (size_t)3 * HEAD * EMB);           // 256 KB
    float* Opart = lpart + (size_t)KSPLIT * ROWS_TOTAL;             // 16 MB

    wprep_kernel<<<dim3(16, 3), 256, 0, stream>>>(Wq, Wk, Wv, Wf);
    qkv_mfma<<<dim3(512), 512, 0, stream>>>(x, Wf, bq, bk, bv, Qb, Kf, Vf);
    attn_mfma<<<dim3(64, KSPLIT), 512, 0, stream>>>(Qb, Kf, Vf, Opart, lpart);
    reduce_kernel<<<dim3((ROWS_TOTAL * HEAD) / 256), 256, 0, stream>>>(Opart, lpart, out);
}

// Round 11
// 118.542 us; speedup vs baseline: 1.0573x; 1.0573x over previous
//
#include <hip/hip_runtime.h>
#include <hip/hip_bf16.h>

#define ROWS_TOTAL 8192   // 4 * 2048
#define EMB 1024
#define HEAD 64
#define SEQ 2048
#define KSPLIT 8                // attn k-chunks (blockIdx.y)
#define KC (SEQ / KSPLIT)       // 256 keys per attn block
#define KT 64                   // keys per staged attn tile

typedef __attribute__((ext_vector_type(8))) short short8;   // 8 bf16 = 4 VGPRs
typedef __attribute__((ext_vector_type(4))) float f32x4;

#define MFMA16(a, b, c) __builtin_amdgcn_mfma_f32_16x16x32_bf16((a), (b), (c), 0, 0, 0)

static __device__ __forceinline__ unsigned short f2bf(float f) {
    union { float f; unsigned u; } v; v.f = f;
    unsigned r = v.u + 0x7fff + ((v.u >> 16) & 1);   // RNE
    return (unsigned short)(r >> 16);
}

// packed f32x2 -> bf16x2 (v_cvt_pk_bf16_f32 on gfx950): low16 = a, high16 = b
static __device__ __forceinline__ unsigned pk2(float a, float b) {
    __hip_bfloat162 h = __float22bfloat162_rn(float2{a, b});
    union { __hip_bfloat162 h; unsigned u; } v; v.h = h;
    return v.u;
}

// ---------------------------------------------------------------------------
// Kernel 0: W[1024][64] x3 -> Wf bf16 in MFMA B-FRAGMENT ORDER (R8-verified):
//   Wf[kc32][tile][ln][quad][8elt]; a wave's B-frag load = dense 1 KB.
// grid = (16 k-slabs, 3 mats) x 256.
// ---------------------------------------------------------------------------
__global__ __launch_bounds__(256) void wprep_kernel(
    const float* __restrict__ Wq, const float* __restrict__ Wk,
    const float* __restrict__ Wv, unsigned short* __restrict__ Wf)
{
    __shared__ float Tr[64][65];
    const int m  = blockIdx.y;
    const int k0 = blockIdx.x * 64;
    const float* __restrict__ W = (m == 0) ? Wq : (m == 1) ? Wk : Wv;
    const int t = threadIdx.x;

    #pragma unroll
    for (int j = 0; j < 4; ++j) {
        int flat = j * 1024 + t * 4;          // 0..4095
        int k = flat >> 6, n = flat & 63;
        float4 w4 = *(const float4*)&W[(size_t)(k0 + k) * 64 + n];
        Tr[n + 0][k] = w4.x; Tr[n + 1][k] = w4.y;
        Tr[n + 2][k] = w4.z; Tr[n + 3][k] = w4.w;
    }
    __syncthreads();

    const int n   = t >> 2;                   // col 0..63
    const int k16 = t & 3;                    // 16-k chunk within slab
    union { short8 s; unsigned u[4]; } o0, o1;
    #pragma unroll
    for (int i = 0; i < 4; ++i) {
        o0.u[i] = pk2(Tr[n][k16 * 16 + 2 * i],     Tr[n][k16 * 16 + 2 * i + 1]);
        o1.u[i] = pk2(Tr[n][k16 * 16 + 8 + 2 * i], Tr[n][k16 * 16 + 9 + 2 * i]);
    }
    const int tile = m * 4 + (n >> 4);
    const int ln   = n & 15;
    const int kc32 = (k0 >> 5) + (k16 >> 1);
    const int half = k16 & 1;
    size_t off = ((size_t)(kc32 * 12 + tile) * 16 + ln) * 32 + half * 16;
    *(short8*)&Wf[off]     = o0.s;
    *(short8*)&Wf[off + 8] = o1.s;
}

// ---------------------------------------------------------------------------
// Kernel 1: QKV projection (R8-verified, byte-identical). Block = 512
// (8 waves), grid = 512 (16 rows each). Cooperative X staging, dense Wf
// B-frags, kh pair-reduce. Q pre-scaled by 0.125*log2(e); V transposed
// through LDS to Vt[b][d][s].
// ---------------------------------------------------------------------------
__global__ __launch_bounds__(512) void qkv_mfma(
    const float* __restrict__ x, const unsigned short* __restrict__ Wf,
    const float* __restrict__ bq, const float* __restrict__ bk,
    const float* __restrict__ bv,
    unsigned short* __restrict__ Qb, unsigned short* __restrict__ Kb,
    unsigned short* __restrict__ Vt)
{
    __shared__ unsigned short Xl[16][136];     // 4.25 KB staged X (272B rows)
    __shared__ f32x4 pr[4][3][64];             // 12 KB kh=1 partials
    __shared__ unsigned short vlds[64][20];

    const int t    = threadIdx.x;
    const int w    = t >> 6;
    const int lane = t & 63;
    const int ln   = lane & 15;
    const int quad = lane >> 4;
    const int m0   = blockIdx.x * 16;
    const int cg   = w >> 1;                   // col group 0..3
    const int kh   = w & 1;                    // k sub-half

    const f32x4 zero = (f32x4){0.f, 0.f, 0.f, 0.f};
    f32x4 acc[3];
    #pragma unroll
    for (int j = 0; j < 3; ++j) acc[j] = zero;

    // staging map: thread -> (row, 4 floats), coalesced within rows
    const int srow = t >> 5;                   // 0..15
    const int scol = (t & 31) * 4;             // 0..124
    const float* __restrict__ xsrc = x + (size_t)(m0 + srow) * EMB + scol;

    for (int kt = 0; kt < EMB; kt += 128) {
        float4 xv = *(const float4*)(xsrc + kt);
        uint2 pk; pk.x = pk2(xv.x, xv.y); pk.y = pk2(xv.z, xv.w);
        *(uint2*)&Xl[srow][scol] = pk;
        __syncthreads();

        #pragma unroll
        for (int cc = 0; cc < 2; ++cc) {
            short8 af = *(const short8*)&Xl[ln][kh * 64 + cc * 32 + quad * 8];
            const int kc32 = (kt >> 5) + kh * 2 + cc;
            #pragma unroll
            for (int j = 0; j < 3; ++j) {
                const int tile = cg * 3 + j;
                short8 bf = *(const short8*)
                    (Wf + ((size_t)(kc32 * 12 + tile) * 16 + ln) * 32 + quad * 8);
                acc[j] = MFMA16(af, bf, acc[j]);
            }
        }
        __syncthreads();
    }

    if (kh == 1) {
        #pragma unroll
        for (int j = 0; j < 3; ++j) pr[cg][j][lane] = acc[j];
    }
    __syncthreads();

    if (kh == 0) {
        const float qs = 0.125f * 1.44269504f;   // softmax scale * log2(e)
        #pragma unroll
        for (int j = 0; j < 3; ++j) {
            acc[j] += pr[cg][j][lane];
            const int tile = cg * 3 + j;
            const int mat  = tile >> 2;
            const int d    = (tile & 3) * 16 + ln;
            const float* bp = (mat == 0) ? bq : (mat == 1) ? bk : bv;
            const float bias = bp[d];
            #pragma unroll
            for (int r = 0; r < 4; ++r) {
                float vfull = acc[j][r] + bias;
                int row = m0 + quad * 4 + r;
                if (mat == 0)      Qb[(size_t)row * 64 + d] = f2bf(vfull * qs);
                else if (mat == 1) Kb[(size_t)row * 64 + d] = f2bf(vfull);
                else               vlds[d][quad * 4 + r] = f2bf(vfull);
            }
        }
    }
    __syncthreads();

    if (t < 256) {   // coalesced transposed V store: Vt[b][d][s]
        const int b  = m0 >> 11;
        const int s0 = m0 & 2047;
        const int d  = t >> 2;
        const int sq = (t & 3) * 4;
        ushort4 pk = {vlds[d][sq + 0], vlds[d][sq + 1],
                      vlds[d][sq + 2], vlds[d][sq + 3]};
        *(ushort4*)&Vt[((size_t)b * 64 + d) * SEQ + s0 + sq] = pk;
    }
}

// ---------------------------------------------------------------------------
// Kernel 2: MFMA flash attention, block-cooperative LDS staging (R7/R8 core)
// with 2 Q-TILES PER WAVE: block = 256 (4 waves), wave w owns q-rows
// [bx*128 + w*32, +32). Every K/V fragment read from LDS now feeds TWO
// MFMAs (one per q-tile) — per-block LDS reads drop 160 -> 96 b128 per
// 64-key tile. Staging identical to R8 (512 dense b128 slots, 2 per thread).
// grid = (64 q-blocks, 8 k-chunks).
// ---------------------------------------------------------------------------
__global__ __launch_bounds__(256) void attn_mfma(
    const unsigned short* __restrict__ Qb, const unsigned short* __restrict__ Kb,
    const unsigned short* __restrict__ Vt,
    float* __restrict__ Opart, float* __restrict__ lpart)
{
    __shared__ unsigned short Kl[KT][72];        // 9.2 KB  [key][d]
    __shared__ unsigned short Vl[HEAD][72];      // 9.2 KB  [d][key] (V^T)
    __shared__ unsigned short Plds[4][32][72];   // 18.4 KB per-wave P (32 q-rows)

    const int t    = threadIdx.x;
    const int w    = t >> 6;
    const int lane = t & 63;
    const int ln   = lane & 15;
    const int quad = lane >> 4;

    const int c  = blockIdx.y;                   // k-chunk
    const int q0 = blockIdx.x * 128 + w * 32;    // this wave's 32 q-rows
    const int b  = blockIdx.x >> 4;              // batch (128 rows/block)

    // Q A-fragments for both q-tiles (pre-scaled in qkv)
    short8 qa0[2], qa1[2];
    #pragma unroll
    for (int qt = 0; qt < 2; ++qt) {
        const unsigned short* qbase =
            Qb + (size_t)(q0 + qt * 16 + ln) * 64 + quad * 8;
        qa0[qt] = *(const short8*)(qbase);
        qa1[qt] = *(const short8*)(qbase + 32);
    }

    const f32x4 zero = (f32x4){0.f, 0.f, 0.f, 0.f};
    f32x4 O[2][4];
    #pragma unroll
    for (int qt = 0; qt < 2; ++qt)
        #pragma unroll
        for (int j = 0; j < 4; ++j) O[qt][j] = zero;
    float lacc[2][4] = {};

    // staging: 512 dense 16B slots per matrix, 2 slots per thread
    // slot s: row = s>>3 (key for K, d for V), off = (s&7)*8
    const int r0 = t >> 3,        o0v = (t & 7) * 8;          // slot t
    const int r1 = (t + 256) >> 3, o1v = ((t + 256) & 7) * 8; // slot t+256
    const unsigned short* Ksrc0 = Kb + ((size_t)b * SEQ + c * KC + r0) * 64 + o0v;
    const unsigned short* Ksrc1 = Kb + ((size_t)b * SEQ + c * KC + r1) * 64 + o1v;
    const unsigned short* Vsrc0 = Vt + ((size_t)b * 64 + r0) * SEQ + c * KC + o0v;
    const unsigned short* Vsrc1 = Vt + ((size_t)b * 64 + r1) * SEQ + c * KC + o1v;

    unsigned short* P = &Plds[w][0][0];

    for (int kt = 0; kt < KC; kt += KT) {
        *(short8*)&Kl[r0][o0v] = *(const short8*)(Ksrc0 + (size_t)kt * 64);
        *(short8*)&Kl[r1][o1v] = *(const short8*)(Ksrc1 + (size_t)kt * 64);
        *(short8*)&Vl[r0][o0v] = *(const short8*)(Vsrc0 + kt);
        *(short8*)&Vl[r1][o1v] = *(const short8*)(Vsrc1 + kt);
        __syncthreads();

        // ---- QK^T: 4 key-subtiles; each K-frag read feeds both q-tiles
        f32x4 s[2][4];
        #pragma unroll
        for (int sub = 0; sub < 4; ++sub) {
            short8 kb0 = *(const short8*)&Kl[sub * 16 + ln][quad * 8];
            short8 kb1 = *(const short8*)&Kl[sub * 16 + ln][32 + quad * 8];
            #pragma unroll
            for (int qt = 0; qt < 2; ++qt) {
                s[qt][sub] = MFMA16(qa0[qt], kb0, zero);
                s[qt][sub] = MFMA16(qa1[qt], kb1, s[qt][sub]);
            }
        }

        // ---- p = exp2(s); denominator; stage P (C-layout -> A-layout)
        #pragma unroll
        for (int qt = 0; qt < 2; ++qt) {
            #pragma unroll
            for (int r = 0; r < 4; ++r) {
                float p0 = __builtin_amdgcn_exp2f(s[qt][0][r]);
                float p1 = __builtin_amdgcn_exp2f(s[qt][1][r]);
                float p2 = __builtin_amdgcn_exp2f(s[qt][2][r]);
                float p3 = __builtin_amdgcn_exp2f(s[qt][3][r]);
                lacc[qt][r] += (p0 + p1) + (p2 + p3);
                unsigned u01 = pk2(p0, p1);
                unsigned u23 = pk2(p2, p3);
                unsigned short* prow = P + (qt * 16 + quad * 4 + r) * 72;
                prow[ln]      = (unsigned short)u01;
                prow[16 + ln] = (unsigned short)(u01 >> 16);
                prow[32 + ln] = (unsigned short)u23;
                prow[48 + ln] = (unsigned short)(u23 >> 16);
            }
        }
        short8 pa0[2], pa1[2];
        #pragma unroll
        for (int qt = 0; qt < 2; ++qt) {
            pa0[qt] = *(const short8*)&Plds[w][qt * 16 + ln][quad * 8];
            pa1[qt] = *(const short8*)&Plds[w][qt * 16 + ln][32 + quad * 8];
        }

        // ---- PV: 4 d-tiles; each V-frag read feeds both q-tiles
        #pragma unroll
        for (int j = 0; j < 4; ++j) {
            short8 vb0 = *(const short8*)&Vl[j * 16 + ln][quad * 8];
            short8 vb1 = *(const short8*)&Vl[j * 16 + ln][32 + quad * 8];
            #pragma unroll
            for (int qt = 0; qt < 2; ++qt) {
                O[qt][j] = MFMA16(pa0[qt], vb0, O[qt][j]);
                O[qt][j] = MFMA16(pa1[qt], vb1, O[qt][j]);
            }
        }
        __syncthreads();
    }

    // denominator: reduce across the 16 key-columns of each C tile
    #pragma unroll
    for (int m = 1; m < 16; m <<= 1) {
        #pragma unroll
        for (int qt = 0; qt < 2; ++qt)
            #pragma unroll
            for (int r = 0; r < 4; ++r) lacc[qt][r] += __shfl_xor(lacc[qt][r], m);
    }

    #pragma unroll
    for (int qt = 0; qt < 2; ++qt) {
        float* __restrict__ ob = Opart + ((size_t)c * ROWS_TOTAL + q0 + qt * 16) * 64;
        #pragma unroll
        for (int j = 0; j < 4; ++j)
            #pragma unroll
            for (int r = 0; r < 4; ++r)
                ob[(size_t)(quad * 4 + r) * 64 + j * 16 + ln] = O[qt][j][r];
        if (ln == 0) {
            #pragma unroll
            for (int r = 0; r < 4; ++r)
                lpart[(size_t)c * ROWS_TOTAL + q0 + qt * 16 + quad * 4 + r] = lacc[qt][r];
        }
    }
}

// ---------------------------------------------------------------------------
// Kernel 3: combine k-split partials:  out = sum_c O_c / sum_c l_c
// ---------------------------------------------------------------------------
__global__ __launch_bounds__(256) void reduce_kernel(
    const float* __restrict__ Opart, const float* __restrict__ lpart,
    float* __restrict__ out)
{
    const int idx = blockIdx.x * 256 + threadIdx.x;   // [0, 8192*64)
    const int r   = idx >> 6;
    float osum = 0.f, lsum = 0.f;
    #pragma unroll
    for (int c = 0; c < KSPLIT; ++c) {
        osum += Opart[(size_t)c * ROWS_TOTAL * HEAD + idx];
        lsum += lpart[(size_t)c * ROWS_TOTAL + r];
    }
    out[idx] = osum / lsum;
}

// ---------------------------------------------------------------------------
extern "C" void kernel_launch(void* const* d_in, const int* in_sizes, int n_in,
                              void* d_out, int out_size, void* d_ws, size_t ws_size,
                              hipStream_t stream)
{
    const float* x  = (const float*)d_in[0];
    const float* Wq = (const float*)d_in[1];
    const float* bq = (const float*)d_in[2];
    const float* Wk = (const float*)d_in[3];
    const float* bk = (const float*)d_in[4];
    const float* Wv = (const float*)d_in[5];
    const float* bv = (const float*)d_in[6];
    float* out = (float*)d_out;

    char* ws = (char*)d_ws;
    unsigned short* Qb = (unsigned short*)ws;                       // 1 MB
    unsigned short* Kb = Qb + (size_t)ROWS_TOTAL * HEAD;            // 1 MB
    unsigned short* Vt = Kb + (size_t)ROWS_TOTAL * HEAD;            // 1 MB
    unsigned short* Wf = Vt + (size_t)ROWS_TOTAL * HEAD;            // 384 KB
    float* lpart = (float*)(Wf + (size_t)3 * HEAD * EMB);           // 256 KB
    float* Opart = lpart + (size_t)KSPLIT * ROWS_TOTAL;             // 16 MB

    wprep_kernel<<<dim3(16, 3), 256, 0, stream>>>(Wq, Wk, Wv, Wf);
    qkv_mfma<<<dim3(512), 512, 0, stream>>>(x, Wf, bq, bk, bv, Qb, Kb, Vt);
    attn_mfma<<<dim3(64, KSPLIT), 256, 0, stream>>>(Qb, Kb, Vt, Opart, lpart);
    reduce_kernel<<<dim3((ROWS_TOTAL * HEAD) / 256), 256, 0, stream>>>(Opart, lpart, out);
}